// Round 5
// baseline (649.263 us; speedup 1.0000x reference)
//
#include <hip/hip_runtime.h>

// RNN-T (Transducer) forward loss, N=16, T=256, U=128, V=256, blank=V-1.
// Two-kernel design, v6:
//   1) rnnt_gather_kernel (fused gather+transpose): block = (t, n), lanes
//      walk u. Reads are DRAM-page-local (two 64B lines per 1KB cell,
//      1KB-stride streams). Thread (t,u)'s two products both belong to
//      diagonal e = t+u+1 of the diagonal-major operand buffer:
//        Gd[n][e][u].x   = log2e * blank(t,u)   (vertical move into (t+1,u))
//        Gd[n][e][u+1].y = log2e * emit(t,u)    (horizontal move into (t,u+1))
//      Writes are 4B scattered at 1032B stride -> absorbed by L2 across 4096
//      blocks, 6.3MB writeback. Gd is NOT initialized: the diag kernel's
//      validity masks cover exactly the written components (see proof in
//      rnnt_diag_kernel), so poison only reaches discarded ternary sides.
//   2) rnnt_diag_kernel: anti-diagonal wavefront, 1 wave/example, 2 u/lane.
//      Per diagonal ONE coalesced global_load_dwordx4 per lane
//      ({B(u0),E(u0),B(u1),E(u1)} of row e) through a depth-16 prefetch
//      ring; cross-lane neighbor via DPP wave_shr:1 (VALU-pipe, ~4cy);
//      base-2 log-sum-exp (no 1/ln2 muls on the loop-carried chain).

#define T_DIM 256
#define U_DIM 128
#define V_DIM 256
#define UV (U_DIM * V_DIM)      // 32768
#define E_ROWS 384              // diagonals 0..383 (dstar max 382)
#define NEGF (-1e30f)
#define LOG2E 1.44269504088896340736f
#define LN2F  0.69314718055994530942f

// base-2 log-sum-exp: inputs/outputs scaled by log2(e)
__device__ __forceinline__ float lse2b2(float x, float y) {
    float m = fmaxf(x, y);
    float t = __builtin_amdgcn_exp2f(-fabsf(x - y));
    return m + __builtin_amdgcn_logf(1.0f + t);   // v_log_f32 == log2
}

// shfl_up by 1 across the full 64-lane wave via DPP wave_shr:1 (ctrl 0x138).
// Lane 0 keeps its own value (old == src); consumers mask lane 0 anyway.
__device__ __forceinline__ float wave_shr1(float x) {
    int xi = __float_as_int(x);
    int r = __builtin_amdgcn_update_dpp(xi, xi, 0x138, 0xF, 0xF, false);
    return __int_as_float(r);
}

// Fused gather + diagonal transpose. Reads page-local, writes diagonal-major.
__global__ __launch_bounds__(128) void rnnt_gather_kernel(
        const float* __restrict__ lp, const int* __restrict__ labels,
        float* __restrict__ Gd) {           // float view of float2 Gd[n][e][u]
    const int t = blockIdx.x;               // 0..255 (input row of lp)
    const int n = blockIdx.y;
    const int u = threadIdx.x;              // 0..127

    const float* cell = lp + ((size_t)(n * T_DIM + t) * U_DIM + u) * (size_t)V_DIM;
    const int e = t + u + 1;                // 1..383
    float* row = Gd + ((size_t)n * E_ROWS + e) * (2 * U_DIM);

    // blank(t,u) -> Gd[e][u].x   (float element 2u)
    row[2 * u] = cell[V_DIM - 1] * LOG2E;
    if (u < U_DIM - 1) {
        // emit(t,u) -> Gd[e][u+1].y  (float element 2u+3)
        const int lbl = labels[n * (U_DIM - 1) + u];
        row[2 * u + 3] = cell[lbl] * LOG2E;
    }
}

__global__ __launch_bounds__(64, 1) void rnnt_diag_kernel(
        const float* __restrict__ lp, const float2* __restrict__ Gd,
        const int* __restrict__ lengths, const int* __restrict__ lab_lens,
        float* __restrict__ out, float inv_n) {
    const int n    = blockIdx.x;
    const int lane = threadIdx.x;
    const int u0   = lane * 2;
    const int u1   = u0 + 1;

    // float4 view: row e = 64 float4; lane l owns {B(u0),E(u0),B(u1),E(u1)}
    const float4* Gdn = (const float4*)(Gd + (size_t)n * E_ROWS * U_DIM);

    const int t_len = lengths[n];
    const int u_len = lab_lens[n];
    const int dstar = (t_len - 1) + u_len;   // in [127, 382] here

    // Final blank log-prob: address known at entry -- issue the (cold) HBM
    // load now so its ~900cy latency hides under the whole sweep.
    const float bl = lp[(size_t)n * T_DIM * UV + (size_t)(t_len - 1) * UV
                        + u_len * V_DIM + (V_DIM - 1)];

    float a0 = (lane == 0) ? 0.0f : NEGF;    // alpha[0,0] at diagonal 0 (base-2 scale)
    float a1 = NEGF;
    float res = NEGF;
    if (dstar == 0 && lane == 0) res = a0;   // safety (unreachable here)

    float nb = wave_shr1(a1);                // neighbor a1 from previous lane

    constexpr int PF = 16;
    float4 buf[PF];

    auto issue = [&](int d, int slot) {
        const int e = min(d, E_ROWS - 1);    // clamp for address safety
        buf[slot] = Gdn[(size_t)e * 64 + lane];  // one coalesced dwordx4 / lane
    };

#pragma unroll
    for (int j = 0; j < PF; ++j) issue(1 + j, j);

    // Diagonals d = 1..384 (padded past 382; extras masked to NEGF).
    // Mask <-> written-coverage proof (Gd is uninitialized poison outside):
    //   vb (uses .x = blank(t-1,u)): requires t in [1,T-1]; gather wrote .x
    //     for t in [1,T] at this (e,u). Superset -> always valid when used.
    //   ve (uses .y = emit(t,u-1)):  requires u>=1, t in [0,T-1]; gather
    //     wrote .y for u>=1, t in [0,T-1]. Exact match.
    for (int dd = 1; dd < 385; dd += PF) {
#pragma unroll
        for (int j = 0; j < PF; ++j) {
            const int d = dd + j;                    // slot == j
            const int t0 = d - u0;
            const int t1 = d - u1;
            const bool vb0 = (unsigned)(t0 - 1) < (unsigned)(T_DIM - 1); // t0 in [1,T-1]
            const bool vb1 = (unsigned)(t1 - 1) < (unsigned)(T_DIM - 1);
            const bool ve0 = (u0 >= 1) && ((unsigned)t0 < (unsigned)T_DIM);
            const bool ve1 = ((unsigned)t1 < (unsigned)T_DIM);

            const float pa0 = vb0 ? (a0 + buf[j].x) : NEGF;
            const float pb0 = ve0 ? (nb + buf[j].y) : NEGF;
            const float na0 = lse2b2(pa0, pb0);

            const float pa1 = vb1 ? (a1 + buf[j].z) : NEGF;
            const float pb1 = ve1 ? (a0 + buf[j].w) : NEGF;  // OLD a0
            const float na1 = lse2b2(pa1, pb1);

            a0 = na0;
            a1 = na1;
            nb = wave_shr1(a1);                      // for next iteration

            issue(d + PF, j);                        // refill slot

            if (d == dstar) {                        // uniform scalar branch
                if (u_len == u0)      res = na0;
                else if (u_len == u1) res = na1;
            }
        }
    }

    if (lane == (u_len >> 1)) {
        atomicAdd(out, -(res * LN2F + bl) * inv_n);  // rescale base-2 -> natural log
    }
}

extern "C" void kernel_launch(void* const* d_in, const int* in_sizes, int n_in,
                              void* d_out, int out_size, void* d_ws, size_t ws_size,
                              hipStream_t stream) {
    const float* lp      = (const float*)d_in[0];
    const int*   labels  = (const int*)d_in[1];
    const int*   lengths = (const int*)d_in[2];
    const int*   lablens = (const int*)d_in[3];
    float* out = (float*)d_out;
    const int N = in_sizes[2];

    float* Gd = (float*)d_ws;                        // N*384*128*8 B = 6.3 MB

    hipMemsetAsync(d_out, 0, sizeof(float), stream);
    rnnt_gather_kernel<<<dim3(T_DIM, N), dim3(128), 0, stream>>>(lp, labels, Gd);
    rnnt_diag_kernel<<<dim3(N), dim3(64), 0, stream>>>(
        lp, (const float2*)Gd, lengths, lablens, out, 1.0f / (float)N);
}